// Round 7
// baseline (3198.735 us; speedup 1.0000x reference)
//
#include <hip/hip_runtime.h>
#include <math.h>

#define HH 128
#define NPIX 16384
#define BB 8
#define MM 4096
#define NN 16384
#define LRELU_S 0.1f
#define NBLK 256

typedef __attribute__((ext_vector_type(8))) short bf16x8;
typedef __attribute__((ext_vector_type(4))) float f32x4;
typedef __attribute__((address_space(3))) unsigned int as3_u32;
typedef __attribute__((address_space(1))) const unsigned int as1_u32;

__device__ __forceinline__ float leaky_(float v){ return v >= 0.f ? v : LRELU_S*v; }
__device__ __forceinline__ float clamp01(float v){ return fminf(fmaxf(v, 0.f), 1.f); }
__device__ __forceinline__ float clamp02(float v){ return fminf(fmaxf(v, 0.f), 2.f); }
__device__ __forceinline__ unsigned short f2bf(float f){
  unsigned u = __float_as_uint(f);
  u = (u + 0x7FFFu + ((u >> 16) & 1u)) >> 16;
  return (unsigned short)u;
}
__device__ __forceinline__ float bf2f(unsigned short s){
  return __uint_as_float(((unsigned)s) << 16);
}

// ---------- prep: A f32 -> Abf[m][n] bf16 ----------
__global__ __launch_bounds__(256) void k_prep(const float* __restrict__ A_,
                                              unsigned short* __restrict__ Abf){
  size_t i = ((size_t)blockIdx.x*256 + threadIdx.x)*8;
  float4 v0 = *(const float4*)&A_[i];
  float4 v1 = *(const float4*)&A_[i+4];
  unsigned short o[8] = { f2bf(v0.x), f2bf(v0.y), f2bf(v0.z), f2bf(v0.w),
                          f2bf(v1.x), f2bf(v1.y), f2bf(v1.z), f2bf(v1.w) };
  *(uint4*)&Abf[i] = *(uint4*)o;
}

// ---------- dn[b] = ||d[b,:]|| ----------
__global__ __launch_bounds__(256) void k_dn(const float* __restrict__ d, float* __restrict__ dn){
  int b = blockIdx.x, t = threadIdx.x;
  float ss = 0.f;
  for (int m=t; m<MM; m+=256){ float v = d[b*MM + m]; ss += v*v; }
  #pragma unroll
  for (int off=32; off; off>>=1) ss += __shfl_down(ss, off);
  __shared__ float red[4];
  if ((t & 63) == 0) red[t>>6] = ss;
  __syncthreads();
  if (t == 0) dn[b] = sqrtf(red[0]+red[1]+red[2]+red[3]);
}

// ---------- grid barrier (all NBLK blocks co-resident) ----------
__device__ __forceinline__ void gbar(int* cnt, unsigned* gen){
  __syncthreads();
  if (threadIdx.x == 0){
    __threadfence();
    unsigned g = __hip_atomic_load(gen, __ATOMIC_RELAXED, __HIP_MEMORY_SCOPE_AGENT);
    int a = __hip_atomic_fetch_add(cnt, 1, __ATOMIC_ACQ_REL, __HIP_MEMORY_SCOPE_AGENT);
    if (a == NBLK-1){
      __hip_atomic_store(cnt, 0, __ATOMIC_RELAXED, __HIP_MEMORY_SCOPE_AGENT);
      __hip_atomic_store(gen, g+1u, __ATOMIC_RELEASE, __HIP_MEMORY_SCOPE_AGENT);
    } else {
      while (__hip_atomic_load(gen, __ATOMIC_ACQUIRE, __HIP_MEMORY_SCOPE_AGENT) == g)
        __builtin_amdgcn_s_sleep(4);
    }
    __threadfence();
  }
  __syncthreads();
}

// ---------- megakernel ----------
__global__ __launch_bounds__(256) void k_mega(
    const unsigned short* __restrict__ Abf, const float* __restrict__ d_,
    const float* __restrict__ wK, const float* __restrict__ w1, const float* __restrict__ b1,
    const float* __restrict__ w2, const float* __restrict__ b2,
    const float* __restrict__ w3, const float* __restrict__ b3,
    const float* __restrict__ delta, const float* __restrict__ alpha,
    const float* __restrict__ beta, const float* __restrict__ dn,
    float* __restrict__ x, unsigned short* __restrict__ xtt,
    float* __restrict__ rk1, float* __restrict__ e_part, float* __restrict__ d2p,
    float* __restrict__ up, int* bar_cnt, unsigned* bar_gen){
  __shared__ float smem[17408];   // union: conv(10752) / gemm1 stage(16384)+part(1024) / zs(2048)
  __shared__ float wKs[18], w1s[100], w2s[100], w3s[100], bs[6], cf_s[8], red8s[64];
  __shared__ float scal[2];
  int blk = blockIdx.x, t = threadIdx.x;
  // conv aliases
  float (*xs)[128]   = (float(*)[128])&smem[0];
  float (*bufA)[18][128] = (float(*)[18][128])&smem[2560];
  float (*bufB)[14][128] = (float(*)[14][128])&smem[7168];
  // gemm1 aliases
  unsigned short* stg = (unsigned short*)&smem[0];   // [2][16][1024] shorts
  float* part = &smem[16384];                        // [4][16][16]
  // phase-B alias
  float (*zs)[256] = (float(*)[256])&smem[0];        // [8][256]

  for (int i=t;i<18;i+=256) wKs[i]=wK[i];
  for (int i=t;i<100;i+=256){ w1s[i]=w1[i]; w2s[i]=w2[i]; w3s[i]=w3[i]; }
  if (t<2){ bs[t]=b1[t]; bs[2+t]=b2[t]; bs[4+t]=b3[t]; }
  if (t==0){ scal[0] = 2.f*clamp02(alpha[0]); scal[1] = clamp02(beta[0]); }
  __syncthreads();

  int w = t >> 6, lane = t & 63;
  int kg = lane >> 4, col = lane & 15;

  for (int it=0; it<9; ++it){
    // ================= Phase A1: conv chain (slab 4 rows) =================
    {
      int b = blk >> 5, slab = blk & 31, r0 = slab*4;
      for (int idx=t; idx<20*128; idx+=256){
        int i = idx>>7, j = idx&127, ir = r0-8+i;
        xs[i][j] = ((unsigned)ir < 128u) ? x[b*NPIX + ir*HH + j] : 0.f;
      }
      __syncthreads();
      for (int c=0;c<2;++c)
        for (int idx=t; idx<18*128; idx+=256){
          int i = idx>>7, j = idx&127, ir = r0-7+i;
          float s = 0.f;
          if ((unsigned)ir < 128u){
            #pragma unroll
            for (int di=0;di<3;++di)
              #pragma unroll
              for (int dj=0;dj<3;++dj){
                int jj = j+dj-1;
                if ((unsigned)jj < 128u) s += xs[i+di][jj]*wKs[(c*3+di)*3+dj];
              }
          }
          bufA[c][i][j] = s;
        }
      __syncthreads();
      for (int o=0;o<2;++o)
        for (int idx=t; idx<14*128; idx+=256){
          int i = idx>>7, j = idx&127, ir = r0-5+i;
          float v = 0.f;
          if ((unsigned)ir < 128u){
            float s = bs[o];
            #pragma unroll
            for (int c=0;c<2;++c)
              #pragma unroll
              for (int di=0;di<5;++di)
                #pragma unroll
                for (int dj=0;dj<5;++dj){
                  int jj = j+dj-2;
                  if ((unsigned)jj < 128u) s += bufA[c][i+di][jj]*w1s[(o*2+c)*25+di*5+dj];
                }
            v = bufA[o][i+2][j] + leaky_(s);
          }
          bufB[o][i][j] = v;
        }
      __syncthreads();
      for (int o=0;o<2;++o)
        for (int idx=t; idx<10*128; idx+=256){
          int i = idx>>7, j = idx&127, ir = r0-3+i;
          float v = 0.f;
          if ((unsigned)ir < 128u){
            float s = bs[2+o];
            #pragma unroll
            for (int c=0;c<2;++c)
              #pragma unroll
              for (int di=0;di<5;++di)
                #pragma unroll
                for (int dj=0;dj<5;++dj){
                  int jj = j+dj-2;
                  if ((unsigned)jj < 128u) s += bufB[c][i+di][jj]*w2s[(o*2+c)*25+di*5+dj];
                }
            v = bufB[o][i+2][j] + leaky_(s);
          }
          bufA[o][i][j] = v;
        }
      __syncthreads();
      for (int o=0;o<2;++o)
        for (int idx=t; idx<6*128; idx+=256){
          int i = idx>>7, j = idx&127, ir = r0-1+i;
          float v = 0.f;
          if ((unsigned)ir < 128u){
            float s = bs[4+o];
            #pragma unroll
            for (int c=0;c<2;++c)
              #pragma unroll
              for (int di=0;di<5;++di)
                #pragma unroll
                for (int dj=0;dj<5;++dj){
                  int jj = j+dj-2;
                  if ((unsigned)jj < 128u) s += bufA[c][i+di][jj]*w3s[(o*2+c)*25+di*5+dj];
                }
            v = bufA[o][i+2][j] + leaky_(s);
          }
          bufB[o][i][j] = v;
        }
      __syncthreads();
      for (int c=0;c<2;++c)
        for (int idx=t; idx<6*128; idx+=256){
          int i = idx>>7, j = idx&127, ir = r0-1+i;
          float v = 0.f;
          if ((unsigned)ir < 128u){
            float kx = 0.f;
            #pragma unroll
            for (int di=0;di<3;++di)
              #pragma unroll
              for (int dj=0;dj<3;++dj){
                int jj = j+dj-1;
                if ((unsigned)jj < 128u) kx += xs[i+6+di][jj]*wKs[(c*3+di)*3+dj];
              }
            v = scal[0]*(kx - bufB[c][i][j]);
          }
          bufA[c][i][j] = v;
        }
      __syncthreads();
      for (int idx=t; idx<4*128; idx+=256){
        int i = idx>>7, j = idx&127, ir = r0+i;
        float s = 0.f;
        #pragma unroll
        for (int c=0;c<2;++c)
          #pragma unroll
          for (int di=0;di<3;++di)
            #pragma unroll
            for (int dj=0;dj<3;++dj){
              int jj = j+dj-1;
              if ((unsigned)jj < 128u) s += bufA[c][i+di][jj]*wKs[(c*3+(2-di))*3+(2-dj)];
            }
        rk1[b*NPIX + ir*HH + j] = s;
      }
      __syncthreads();   // conv LDS free before gemm1 staging
    }
    // ================= Phase A2: gemm1 (LDS-staged MFMA) =================
    {
      int mg = blk >> 4, ng = blk & 15;
      int n0 = ng*1024;
      // stage tile: 16 rows x 1024 cols, rows of 2048B, XOR-swizzled (R5-proven)
      auto STAGE1 = [&](int tile, int buf){
        #pragma unroll
        for (int q=0;q<8;++q){
          int R = w*8+q;                 // 1 KiB region
          int row = R>>1, h = R&1;
          int c16 = h*64 + lane;         // dest 16B-chunk in row
          int s16 = c16 ^ (row & 7);     // swizzled source chunk
          const unsigned short* gp = Abf + (size_t)(mg*256 + tile*16 + row)*NN + n0 + s16*8;
          __builtin_amdgcn_global_load_lds((as1_u32*)gp,
              (as3_u32*)(stg + buf*16384 + R*512), 16, 0, 0);
        }
      };
      STAGE1(0,0);
      for (int tile=0; tile<16; ++tile){
        __syncthreads();                 // stage of 'tile' complete (vmcnt drained)
        if (tile<15) STAGE1(tile+1, (tile+1)&1);
        int buf = tile & 1;
        f32x4 acc = {0.f,0.f,0.f,0.f};
        #pragma unroll
        for (int j=0;j<8;++j){
          int cbyte = w*512 + j*64 + kg*16;
          bf16x8 a = *(const bf16x8*)((char*)stg + buf*32768 + col*2048 + (cbyte ^ ((col&7)<<4)));
          int nb = n0 + w*256 + j*32;
          bf16x8 bfr = *(const bf16x8*)(xtt + ((size_t)(nb>>3) + kg)*128 + col*8);
          acc = __builtin_amdgcn_mfma_f32_16x16x32_bf16(a, bfr, acc, 0, 0, 0);
        }
        #pragma unroll
        for (int jj=0;jj<4;++jj) part[w*256 + (kg*4+jj)*16 + col] = acc[jj];
        __syncthreads();
        {
          int r = t >> 4, b = t & 15;
          float s = part[r*16+b] + part[256 + r*16+b] + part[512 + r*16+b] + part[768 + r*16+b];
          int m = mg*256 + tile*16 + r;
          float val = s - ((ng==0 && b<8) ? d_[b*MM + m] : 0.f);
          e_part[((size_t)ng*MM + m)*16 + b] = val;
        }
      }
    }
    gbar(bar_cnt, bar_gen);
    // ================= Phase B: e-reduce, d2p, u = A^T e =================
    {
      int mg = blk >> 4, ng = blk & 15;
      int m0 = mg*256, n0 = ng*1024;
      // reduce e over 16 ng-partials into zs[b][ml]
      #pragma unroll
      for (int k2=0;k2<8;++k2){
        int idx = k2*256 + t;            // 2048 = 256 ml x 8 b
        int ml = idx >> 3, b = idx & 7;
        float s = 0.f;
        #pragma unroll
        for (int p=0;p<16;++p) s += e_part[((size_t)p*MM + m0 + ml)*16 + b];
        zs[b][ml] = s;
      }
      __syncthreads();
      if (ng == 0){                      // d2p[mg][b] = sum e^2 over this m-slice
        if (t < 64){
          int b = t & 7, grp = t >> 3;
          float s = 0.f;
          #pragma unroll
          for (int i=0;i<32;++i){ float v = zs[b][grp*32+i]; s += v*v; }
          red8s[grp*8 + b] = s;
        }
        __syncthreads();
        if (t < 8){
          float s2 = 0.f;
          #pragma unroll
          for (int g2=0;g2<8;++g2) s2 += red8s[g2*8 + t];
          d2p[mg*8 + t] = s2;
        }
      }
      // u-partial: rows [m0 + h*128, +128), cols [n0 + (t&127)*8, +8)
      int h = t >> 7, cth = t & 127;
      const unsigned short* Ap = Abf + (size_t)(m0 + h*128)*NN + n0 + cth*8;
      float acc[8][8];
      #pragma unroll
      for (int c=0;c<8;++c)
        #pragma unroll
        for (int b=0;b<8;++b) acc[c][b] = 0.f;
      for (int mo=0; mo<128; mo+=8){
        uint4 a8[8];
        #pragma unroll
        for (int u=0;u<8;++u) a8[u] = *(const uint4*)(Ap + (size_t)(mo+u)*NN);
        #pragma unroll
        for (int u=0;u<8;++u){
          float av[8];
          av[0]=bf2f((unsigned short)(a8[u].x & 0xffff)); av[1]=bf2f((unsigned short)(a8[u].x >> 16));
          av[2]=bf2f((unsigned short)(a8[u].y & 0xffff)); av[3]=bf2f((unsigned short)(a8[u].y >> 16));
          av[4]=bf2f((unsigned short)(a8[u].z & 0xffff)); av[5]=bf2f((unsigned short)(a8[u].z >> 16));
          av[6]=bf2f((unsigned short)(a8[u].w & 0xffff)); av[7]=bf2f((unsigned short)(a8[u].w >> 16));
          int ml = h*128 + mo + u;
          #pragma unroll
          for (int b=0;b<8;++b){
            float z = zs[b][ml];
            #pragma unroll
            for (int c=0;c<8;++c) acc[c][b] += av[c]*z;
          }
        }
      }
      int pg = mg*2 + h;                 // 32 m-partials
      #pragma unroll
      for (int b=0;b<8;++b){
        float4 v0 = {acc[0][b], acc[1][b], acc[2][b], acc[3][b]};
        float4 v1 = {acc[4][b], acc[5][b], acc[6][b], acc[7][b]};
        float* dst = &up[((size_t)pg*8 + b)*NN + n0 + cth*8];
        *(float4*)dst = v0;
        *(float4*)(dst+4) = v1;
      }
      __syncthreads();
    }
    gbar(bar_cnt, bar_gen);
    // ================= Phase C: cf + combine + xtt pack =================
    {
      if (t < 8){
        float s2 = 0.f;
        #pragma unroll
        for (int mg2=0;mg2<16;++mg2) s2 += d2p[mg2*8 + t];
        float dist = fmaxf(sqrtf(s2), 1e-10f);
        float de = expf(delta[0]);
        cf_s[t] = scal[0]*(1.f - fminf(1.f, de*dn[t]/dist));
      }
      __syncthreads();
      float bta = scal[1];
      #pragma unroll
      for (int hh=0; hh<2; ++hh){
        int o = hh*65536 + blk*256 + t;  // 131072 outputs
        int b = o >> 14, pix = o & 16383;
        float s = 0.f;
        #pragma unroll
        for (int p=0; p<32; ++p)
          s += up[((size_t)p*8 + b)*NN + pix];
        float total = rk1[b*NPIX + pix] + cf_s[b]*s;
        float xn = clamp01(x[b*NPIX + pix] - bta*total);
        x[b*NPIX + pix] = xn;
        xtt[((size_t)(pix>>3)*16 + b)*8 + (pix&7)] = f2bf(xn);
      }
    }
    if (it < 8) gbar(bar_cnt, bar_gen);
  }
}

extern "C" void kernel_launch(void* const* d_in, const int* in_sizes, int n_in,
                              void* d_out, int out_size, void* d_ws, size_t ws_size,
                              hipStream_t stream) {
  const float* d_d   = (const float*)d_in[0];
  const float* d_A   = (const float*)d_in[1];
  const float* w1    = (const float*)d_in[2];
  const float* b1    = (const float*)d_in[3];
  const float* w2    = (const float*)d_in[4];
  const float* b2    = (const float*)d_in[5];
  const float* w3    = (const float*)d_in[6];
  const float* b3    = (const float*)d_in[7];
  const float* wK    = (const float*)d_in[8];
  const float* delta = (const float*)d_in[9];
  const float* alpha = (const float*)d_in[10];
  const float* beta  = (const float*)d_in[12];

  char* p = (char*)d_ws;
  unsigned short* Abf = (unsigned short*)p; p += (size_t)MM*NN*2;      // 128 MiB
  unsigned short* xtt = (unsigned short*)p; p += (size_t)2048*16*8*2;  // 512 KiB
  float* x      = (float*)p; p += (size_t)BB*NPIX*4;
  float* rk1    = (float*)p; p += (size_t)BB*NPIX*4;
  float* e_part = (float*)p; p += (size_t)16*MM*16*4;                  // 4 MiB
  float* up     = (float*)p; p += (size_t)32*8*NN*4;                   // 16 MiB
  float* d2p    = (float*)p; p += (size_t)16*8*4;
  float* dnb    = (float*)p; p += 64;
  int* bar      = (int*)p;  p += 64;

  k_prep<<<MM*NN/(256*8), 256, 0, stream>>>(d_A, Abf);
  k_dn<<<BB, 256, 0, stream>>>(d_d, dnb);
  hipMemsetAsync(x, 0, (size_t)BB*NPIX*4, stream);
  hipMemsetAsync(xtt, 0, (size_t)2048*16*8*2, stream);
  hipMemsetAsync(bar, 0, 8, stream);

  k_mega<<<NBLK, 256, 0, stream>>>(Abf, d_d, wK, w1, b1, w2, b2, w3, b3,
                                   delta, alpha, beta, dnb,
                                   x, xtt, rk1, e_part, d2p, up,
                                   bar, (unsigned*)(bar+1));

  hipMemcpyAsync(d_out, x, (size_t)BB*NPIX*4, hipMemcpyDeviceToDevice, stream);
}

// Round 8
// 1402.328 us; speedup vs baseline: 2.2810x; 2.2810x over previous
//
#include <hip/hip_runtime.h>
#include <math.h>

#define HH 128
#define NPIX 16384
#define BB 8
#define MM 4096
#define NN 16384
#define LRELU_S 0.1f

typedef __attribute__((ext_vector_type(8))) short bf16x8;
typedef __attribute__((ext_vector_type(4))) float f32x4;

__device__ __forceinline__ float leaky_(float v){ return v >= 0.f ? v : LRELU_S*v; }
__device__ __forceinline__ float clamp01(float v){ return fminf(fmaxf(v, 0.f), 1.f); }
__device__ __forceinline__ float clamp02(float v){ return fminf(fmaxf(v, 0.f), 2.f); }
__device__ __forceinline__ unsigned short f2bf(float f){
  unsigned u = __float_as_uint(f);
  u = (u + 0x7FFFu + ((u >> 16) & 1u)) >> 16;
  return (unsigned short)u;
}
__device__ __forceinline__ float bf2f(unsigned short s){
  return __uint_as_float(((unsigned)s) << 16);
}

// ---------- prep: A f32 -> Abf bf16 ----------
__global__ __launch_bounds__(256) void k_prep(const float* __restrict__ A_,
                                              unsigned short* __restrict__ Abf){
  size_t i = ((size_t)blockIdx.x*256 + threadIdx.x)*8;
  float4 v0 = *(const float4*)&A_[i];
  float4 v1 = *(const float4*)&A_[i+4];
  unsigned short o[8] = { f2bf(v0.x), f2bf(v0.y), f2bf(v0.z), f2bf(v0.w),
                          f2bf(v1.x), f2bf(v1.y), f2bf(v1.z), f2bf(v1.w) };
  *(uint4*)&Abf[i] = *(uint4*)o;
}

// ---------- dn[b] = ||d[b,:]|| ----------
__global__ __launch_bounds__(256) void k_dn(const float* __restrict__ d, float* __restrict__ dn){
  int b = blockIdx.x, t = threadIdx.x;
  float ss = 0.f;
  for (int m=t; m<MM; m+=256){ float v = d[b*MM + m]; ss += v*v; }
  #pragma unroll
  for (int off=32; off; off>>=1) ss += __shfl_down(ss, off);
  __shared__ float red[4];
  if ((t & 63) == 0) red[t>>6] = ss;
  __syncthreads();
  if (t == 0) dn[b] = sqrtf(red[0]+red[1]+red[2]+red[3]);
}

// ---------- K_A: gemm1 partials. 1024 blocks (mt 0..255 x ng 0..3), 256 thr ----------
// Index derivation from R4-proven gemm1mf (8-wave k-split over 2048-col slices):
// here 4 waves k-split a 4096-col slice: k = ng*4096 + w*1024 + s*32 + kg*8.
// A: row (mt*16+col); B (xtt pack [n>>3][b16][8]): group idx = k>>3 = ng*512+w*128+s*4+kg.
__global__ __launch_bounds__(256) void k_gemm1p(const unsigned short* __restrict__ Abf,
    const unsigned short* __restrict__ xtt, float* __restrict__ e_part){
  __shared__ float part[4][16][16];
  int blk = blockIdx.x;
  int mt = blk >> 2, ng = blk & 3;
  int t = threadIdx.x, w = t >> 6, lane = t & 63;
  int kg = lane >> 4, col = lane & 15;
  const unsigned short* Ap = Abf + (size_t)(mt*16 + col)*NN + ng*4096 + w*1024 + kg*8;
  const unsigned short* Bp = xtt + ((size_t)(ng*512 + w*128 + kg)*16 + col)*8;
  f32x4 acc = {0.f,0.f,0.f,0.f};
  #pragma unroll 8
  for (int s=0; s<32; ++s){
    bf16x8 a = *(const bf16x8*)(Ap + s*32);
    bf16x8 b = *(const bf16x8*)(Bp + s*512);
    acc = __builtin_amdgcn_mfma_f32_16x16x32_bf16(a, b, acc, 0, 0, 0);
  }
  #pragma unroll
  for (int j=0;j<4;++j) part[w][kg*4+j][col] = acc[j];
  __syncthreads();
  int r = t >> 4, b = t & 15;
  float s = part[0][r][b] + part[1][r][b] + part[2][r][b] + part[3][r][b];
  e_part[((size_t)ng*MM + mt*16 + r)*16 + b] = s;
}

// ---------- K_B: heterogeneous. blocks 0..511 gemm2 u-partials; 512..639 conv chain ----------
__global__ __launch_bounds__(256) void k_phaseB(const unsigned short* __restrict__ Abf,
    const float* __restrict__ e_part, const float* __restrict__ d_,
    const float* __restrict__ x,
    const float* __restrict__ wK, const float* __restrict__ w1, const float* __restrict__ b1,
    const float* __restrict__ w2, const float* __restrict__ b2,
    const float* __restrict__ w3, const float* __restrict__ b3,
    const float* __restrict__ alpha,
    float* __restrict__ up, float* __restrict__ d2p, float* __restrict__ rk1){
  __shared__ float smem[13312];          // conv: xs(3072)+bufA(5632)+bufB(4608); gemm2: zs(1024)
  __shared__ float wKs[18], w1s[100], w2s[100], w3s[100], bs[6], red8s[64];
  int blk = blockIdx.x, t = threadIdx.x;

  if (blk < 512){
    // ===== gemm2 role: u[ms*2+h][b][n-slice] = sum_m A[m][n] * e[b][m] =====
    float (*zs)[128] = (float(*)[128])smem;
    int ms = blk >> 4, nb = blk & 15;
    int m0 = ms*128, n0 = nb*1024;
    for (int i=t; i<1024; i+=256){
      int ml = i >> 3, b = i & 7;
      int m = m0 + ml;
      float s = e_part[(size_t)(0*MM + m)*16 + b]
              + e_part[(size_t)(1*MM + m)*16 + b]
              + e_part[(size_t)(2*MM + m)*16 + b]
              + e_part[(size_t)(3*MM + m)*16 + b];
      zs[b][ml] = s - d_[b*MM + m];
    }
    __syncthreads();
    if (nb == 0){
      if (t < 64){
        int b = t & 7, g = t >> 3;
        float s = 0.f;
        #pragma unroll
        for (int i=0;i<16;++i){ float v = zs[b][g*16+i]; s += v*v; }
        red8s[g*8 + b] = s;
      }
      __syncthreads();
      if (t < 8){
        float s2 = 0.f;
        #pragma unroll
        for (int g=0;g<8;++g) s2 += red8s[g*8 + t];
        d2p[ms*8 + t] = s2;
      }
    }
    int h = t >> 7, cth = t & 127;       // h: 64-row half; cth: 8-col group
    const unsigned short* Ap = Abf + (size_t)(m0 + h*64)*NN + n0 + cth*8;
    float acc[8][8];                     // [c][b]
    #pragma unroll
    for (int c=0;c<8;++c)
      #pragma unroll
      for (int b=0;b<8;++b) acc[c][b] = 0.f;
    for (int mo=0; mo<64; mo+=8){
      uint4 a8[8];
      #pragma unroll
      for (int u=0;u<8;++u) a8[u] = *(const uint4*)(Ap + (size_t)(mo+u)*NN);
      #pragma unroll
      for (int u=0;u<8;++u){
        float av[8];
        av[0]=bf2f((unsigned short)(a8[u].x & 0xffff)); av[1]=bf2f((unsigned short)(a8[u].x >> 16));
        av[2]=bf2f((unsigned short)(a8[u].y & 0xffff)); av[3]=bf2f((unsigned short)(a8[u].y >> 16));
        av[4]=bf2f((unsigned short)(a8[u].z & 0xffff)); av[5]=bf2f((unsigned short)(a8[u].z >> 16));
        av[6]=bf2f((unsigned short)(a8[u].w & 0xffff)); av[7]=bf2f((unsigned short)(a8[u].w >> 16));
        int ml = h*64 + mo + u;
        #pragma unroll
        for (int b=0;b<8;++b){
          float z = zs[b][ml];
          #pragma unroll
          for (int c=0;c<8;++c) acc[c][b] += av[c]*z;
        }
      }
    }
    int pg = ms*2 + h;                   // 64 m-partials
    #pragma unroll
    for (int b=0;b<8;++b){
      float4 v0 = {acc[0][b], acc[1][b], acc[2][b], acc[3][b]};
      float4 v1 = {acc[4][b], acc[5][b], acc[6][b], acc[7][b]};
      float* dst = &up[((size_t)pg*8 + b)*NN + n0 + cth*8];
      *(float4*)dst = v0;
      *(float4*)(dst+4) = v1;
    }
    return;
  }

  // ===== conv role (R4-proven, 128 blocks: b = cb>>4, slab of 8 rows) =====
  int cb = blk - 512;
  int b = cb >> 4, slab = cb & 15, r0 = slab*8;
  float (*xs)[128] = (float(*)[128])&smem[0];                 // 24 rows
  float (*bufA)[22][128] = (float(*)[22][128])&smem[3072];
  float (*bufB)[18][128] = (float(*)[18][128])&smem[8704];
  float twoa = 2.f*clamp02(alpha[0]);
  for (int i=t;i<18;i+=256) wKs[i]=wK[i];
  for (int i=t;i<100;i+=256){ w1s[i]=w1[i]; w2s[i]=w2[i]; w3s[i]=w3[i]; }
  if (t<2){ bs[t]=b1[t]; bs[2+t]=b2[t]; bs[4+t]=b3[t]; }
  for (int idx=t; idx<24*128; idx+=256){
    int i = idx>>7, j = idx&127, ir = r0-8+i;
    xs[i][j] = ((unsigned)ir < 128u) ? x[b*NPIX + ir*HH + j] : 0.f;
  }
  __syncthreads();
  for (int c=0;c<2;++c)
    for (int idx=t; idx<22*128; idx+=256){
      int i = idx>>7, j = idx&127, ir = r0-7+i;
      float s = 0.f;
      if ((unsigned)ir < 128u){
        #pragma unroll
        for (int di=0;di<3;++di)
          #pragma unroll
          for (int dj=0;dj<3;++dj){
            int jj = j+dj-1;
            if ((unsigned)jj < 128u) s += xs[i+di][jj]*wKs[(c*3+di)*3+dj];
          }
      }
      bufA[c][i][j] = s;
    }
  __syncthreads();
  for (int o=0;o<2;++o)
    for (int idx=t; idx<18*128; idx+=256){
      int i = idx>>7, j = idx&127, ir = r0-5+i;
      float v = 0.f;
      if ((unsigned)ir < 128u){
        float s = bs[o];
        #pragma unroll
        for (int c=0;c<2;++c)
          #pragma unroll
          for (int di=0;di<5;++di)
            #pragma unroll
            for (int dj=0;dj<5;++dj){
              int jj = j+dj-2;
              if ((unsigned)jj < 128u) s += bufA[c][i+di][jj]*w1s[(o*2+c)*25+di*5+dj];
            }
        v = bufA[o][i+2][j] + leaky_(s);
      }
      bufB[o][i][j] = v;
    }
  __syncthreads();
  for (int o=0;o<2;++o)
    for (int idx=t; idx<14*128; idx+=256){
      int i = idx>>7, j = idx&127, ir = r0-3+i;
      float v = 0.f;
      if ((unsigned)ir < 128u){
        float s = bs[2+o];
        #pragma unroll
        for (int c=0;c<2;++c)
          #pragma unroll
          for (int di=0;di<5;++di)
            #pragma unroll
            for (int dj=0;dj<5;++dj){
              int jj = j+dj-2;
              if ((unsigned)jj < 128u) s += bufB[c][i+di][jj]*w2s[(o*2+c)*25+di*5+dj];
            }
        v = bufB[o][i+2][j] + leaky_(s);
      }
      bufA[o][i][j] = v;
    }
  __syncthreads();
  for (int o=0;o<2;++o)
    for (int idx=t; idx<10*128; idx+=256){
      int i = idx>>7, j = idx&127, ir = r0-1+i;
      float v = 0.f;
      if ((unsigned)ir < 128u){
        float s = bs[4+o];
        #pragma unroll
        for (int c=0;c<2;++c)
          #pragma unroll
          for (int di=0;di<5;++di)
            #pragma unroll
            for (int dj=0;dj<5;++dj){
              int jj = j+dj-2;
              if ((unsigned)jj < 128u) s += bufA[c][i+di][jj]*w3s[(o*2+c)*25+di*5+dj];
            }
        v = bufA[o][i+2][j] + leaky_(s);
      }
      bufB[o][i][j] = v;
    }
  __syncthreads();
  for (int c=0;c<2;++c)
    for (int idx=t; idx<10*128; idx+=256){
      int i = idx>>7, j = idx&127, ir = r0-1+i;
      float v = 0.f;
      if ((unsigned)ir < 128u){
        float kx = 0.f;
        #pragma unroll
        for (int di=0;di<3;++di)
          #pragma unroll
          for (int dj=0;dj<3;++dj){
            int jj = j+dj-1;
            if ((unsigned)jj < 128u) kx += xs[i+6+di][jj]*wKs[(c*3+di)*3+dj];
          }
        v = twoa*(kx - bufB[c][i][j]);
      }
      bufA[c][i][j] = v;
    }
  __syncthreads();
  for (int idx=t; idx<8*128; idx+=256){
    int i = idx>>7, j = idx&127, ir = r0+i;
    float s = 0.f;
    #pragma unroll
    for (int c=0;c<2;++c)
      #pragma unroll
      for (int di=0;di<3;++di)
        #pragma unroll
        for (int dj=0;dj<3;++dj){
          int jj = j+dj-1;
          if ((unsigned)jj < 128u) s += bufA[c][i+di][jj]*wKs[(c*3+(2-di))*3+(2-dj)];
        }
    rk1[b*NPIX + ir*HH + j] = s;
  }
}

// ---------- K_C: cf + combine + xtt pack. 512 blocks x 256 thr ----------
__global__ __launch_bounds__(256) void k_combine3(const float* __restrict__ up,
    const float* __restrict__ rk1, const float* __restrict__ d2p,
    const float* __restrict__ dn, const float* __restrict__ delta,
    const float* __restrict__ alpha, const float* __restrict__ beta,
    float* __restrict__ x, unsigned short* __restrict__ xtt){
  __shared__ float cf_s[8];
  int t = threadIdx.x;
  if (t < 8){
    float s2 = 0.f;
    #pragma unroll
    for (int ms=0; ms<32; ++ms) s2 += d2p[ms*8 + t];
    float dist = fmaxf(sqrtf(s2), 1e-10f);
    float de = expf(delta[0]);
    float a = clamp02(alpha[0]);
    cf_s[t] = 2.f*a*(1.f - fminf(1.f, de*dn[t]/dist));
  }
  __syncthreads();
  float bta = clamp02(beta[0]);
  int o = blockIdx.x*256 + t;            // 131072 outputs
  int b = o >> 14, pix = o & 16383;
  float s = 0.f;
  #pragma unroll
  for (int p=0; p<64; ++p)
    s += up[((size_t)p*8 + b)*NN + pix];
  float tot = rk1[b*NPIX + pix] + cf_s[b]*s;
  float xn = clamp01(x[b*NPIX + pix] - bta*tot);
  x[b*NPIX + pix] = xn;
  xtt[((size_t)(pix>>3)*16 + b)*8 + (pix&7)] = f2bf(xn);
}

extern "C" void kernel_launch(void* const* d_in, const int* in_sizes, int n_in,
                              void* d_out, int out_size, void* d_ws, size_t ws_size,
                              hipStream_t stream) {
  const float* d_d   = (const float*)d_in[0];
  const float* d_A   = (const float*)d_in[1];
  const float* w1    = (const float*)d_in[2];
  const float* b1    = (const float*)d_in[3];
  const float* w2    = (const float*)d_in[4];
  const float* b2    = (const float*)d_in[5];
  const float* w3    = (const float*)d_in[6];
  const float* b3    = (const float*)d_in[7];
  const float* wK    = (const float*)d_in[8];
  const float* delta = (const float*)d_in[9];
  const float* alpha = (const float*)d_in[10];
  const float* beta  = (const float*)d_in[12];

  char* p = (char*)d_ws;
  unsigned short* Abf = (unsigned short*)p; p += (size_t)MM*NN*2;      // 128 MiB
  unsigned short* xtt = (unsigned short*)p; p += (size_t)2048*16*8*2;  // 512 KiB
  float* x      = (float*)p; p += (size_t)BB*NPIX*4;
  float* rk1    = (float*)p; p += (size_t)BB*NPIX*4;
  float* e_part = (float*)p; p += (size_t)4*MM*16*4;                   // 1 MiB
  float* up     = (float*)p; p += (size_t)64*8*NN*4;                   // 32 MiB
  float* d2p    = (float*)p; p += (size_t)32*8*4;
  float* dnb    = (float*)p; p += 64;

  k_prep<<<MM*NN/(256*8), 256, 0, stream>>>(d_A, Abf);
  k_dn<<<BB, 256, 0, stream>>>(d_d, dnb);
  hipMemsetAsync(x, 0, (size_t)BB*NPIX*4, stream);
  hipMemsetAsync(xtt, 0, (size_t)2048*16*8*2, stream);

  for (int it=0; it<9; ++it){
    k_gemm1p<<<1024, 256, 0, stream>>>(Abf, xtt, e_part);
    k_phaseB<<<640, 256, 0, stream>>>(Abf, e_part, d_d, x,
                                      wK, w1, b1, w2, b2, w3, b3, alpha,
                                      up, d2p, rk1);
    k_combine3<<<512, 256, 0, stream>>>(up, rk1, d2p, dnb, delta, alpha, beta, x, xtt);
  }

  hipMemcpyAsync(d_out, x, (size_t)BB*NPIX*4, hipMemcpyDeviceToDevice, stream);
}